// Round 12
// baseline (1061.313 us; speedup 1.0000x reference)
//
#include <hip/hip_runtime.h>
#include <math.h>

#define BB 16
#define NN 2000
#define CH 128
#define KNN 8
#define JCH 8
#define JSZ 250  // NN / JCH

// ---------------------------------------------------------------------------
// helpers
// ---------------------------------------------------------------------------
__device__ inline float wred(float v) {
    for (int off = 32; off > 0; off >>= 1) v += __shfl_down(v, off, 64);
    return v;
}

// conv1: c1[b,o,n] = sum_c w1a[o,c]*data[b,n,c] + b1a[o]
__global__ void k_conv1(const float* __restrict__ data, const float* __restrict__ w1a,
                        const float* __restrict__ b1a, float* __restrict__ c1) {
    int i = blockIdx.x * 256 + threadIdx.x;  // (b*128+o)*N+n
    if (i >= BB * CH * NN) return;
    int n = i % NN;
    int rest = i / NN;
    int o = rest & 127;
    int b = rest >> 7;
    const float* dp = data + (b * NN + n) * 4;
    float acc = b1a[o];
    for (int c = 0; c < 4; ++c) acc += w1a[o * 4 + c] * dp[c];
    c1[i] = acc;
}

// per-channel bn stats over (b,n): 128 blocks
__global__ void k_chanstats(const float* __restrict__ src, float* __restrict__ chAB) {
    int o = blockIdx.x;
    int tid = threadIdx.x;
    float s = 0.f, ss = 0.f;
    for (int b = 0; b < BB; ++b) {
        const float* p = src + (b * CH + o) * NN;
        for (int n = tid; n < NN; n += 256) { float v = p[n]; s += v; ss += v * v; }
    }
    s = wred(s); ss = wred(ss);
    __shared__ float sh[8];
    int wid = tid >> 6, lane = tid & 63;
    if (lane == 0) { sh[wid] = s; sh[4 + wid] = ss; }
    __syncthreads();
    if (tid == 0) {
        float S0 = sh[0] + sh[1] + sh[2] + sh[3];
        float SS = sh[4] + sh[5] + sh[6] + sh[7];
        float m = S0 / (float)(BB * NN);
        float var = SS / (float)(BB * NN) - m * m;
        float a = rsqrtf(var + 1e-5f);
        chAB[o] = a;
        chAB[CH + o] = -m * a;
    }
}

// ---------------------------------------------------------------------------
// generic 128x128 GEMM over columns (b,n), with input transform.
// FMA accumulation order IDENTICAL to the r3 baseline — do not reorder.
// ---------------------------------------------------------------------------
__global__ __launch_bounds__(256) void k_gemm(const float* __restrict__ X, const float* __restrict__ W,
                                              const float* __restrict__ bias, float* __restrict__ Y,
                                              const float* __restrict__ ab, int mode) {
    int ot = blockIdx.x, by = blockIdx.y;
    int b = by >> 5, nt = by & 31;
    int n0 = nt * 64, o0 = ot * 64;
    int tid = threadIdx.x;
    int tx = tid & 15, ty = tid >> 4;
    __shared__ float Xs[32][64];
    __shared__ float Ws[32][68];
    float acc[4][4] = {};
    for (int jc = 0; jc < 4; ++jc) {
        for (int q = 0; q < 8; ++q) {
            int e = q * 256 + tid;
            int jj = e >> 6, nn = e & 63;
            int j = jc * 32 + jj, n = n0 + nn;
            float v = 0.f;
            if (n < NN) {
                v = X[(b * CH + j) * NN + n];
                if (mode == 1) v = fmaxf(ab[j] * v + ab[CH + j], 0.f);
                else if (mode == 2) { int bc = b * CH + j; v = fmaxf(ab[bc * 2] * v + ab[bc * 2 + 1], 0.f); }
            }
            Xs[jj][nn] = v;
        }
        for (int q = 0; q < 8; ++q) {
            int e = q * 256 + tid;
            int jj = e & 31, oo = e >> 5;
            Ws[jj][oo] = W[(o0 + oo) * CH + jc * 32 + jj];
        }
        __syncthreads();
        for (int jj = 0; jj < 32; ++jj) {
            float4 wv = *(const float4*)&Ws[jj][ty * 4];
            float4 xv = *(const float4*)&Xs[jj][tx * 4];
            float wva[4] = {wv.x, wv.y, wv.z, wv.w};
            float xva[4] = {xv.x, xv.y, xv.z, xv.w};
#pragma unroll
            for (int a = 0; a < 4; ++a)
#pragma unroll
                for (int bq = 0; bq < 4; ++bq) acc[a][bq] += wva[a] * xva[bq];
        }
        __syncthreads();
    }
    for (int a = 0; a < 4; ++a) {
        int o = o0 + ty * 4 + a;
        float bi = bias[o];
        for (int q = 0; q < 4; ++q) {
            int n = n0 + tx * 4 + q;
            if (n < NN) Y[(b * CH + o) * NN + n] = acc[a][q] + bi;
        }
    }
}

// ---------------------------------------------------------------------------
// stage 1 tail: channel-norm, S, D, f5
// ---------------------------------------------------------------------------
__global__ void k_invn(const float* __restrict__ h2, float* __restrict__ invn) {
    int b = blockIdx.x >> 3, chunk = blockIdx.x & 7;
    int n = chunk * 256 + threadIdx.x;
    if (n >= NN) return;
    float acc = 0.f;
    for (int c = 0; c < CH; ++c) { float v = h2[(b * CH + c) * NN + n]; acc += v * v; }
    invn[b * NN + n] = 1.f / (sqrtf(acc) + 1e-5f);
}

__global__ void k_S(const float* __restrict__ h2, const float* __restrict__ invn, float* __restrict__ Sv) {
    int row = blockIdx.x;  // b*128+c
    int b = row >> 7;
    const float* p = h2 + row * NN;
    const float* iv = invn + b * NN;
    float s = 0.f;
    for (int n = threadIdx.x; n < NN; n += 256) s += p[n] * iv[n];
    s = wred(s);
    __shared__ float sh[4];
    int wid = threadIdx.x >> 6, lane = threadIdx.x & 63;
    if (lane == 0) sh[wid] = s;
    __syncthreads();
    if (threadIdx.x == 0) Sv[row] = sh[0] + sh[1] + sh[2] + sh[3];
}

__global__ void k_Df(const float* __restrict__ h2, const float* __restrict__ invn,
                     const float* __restrict__ Sv, const float* __restrict__ data,
                     float* __restrict__ outD, float* __restrict__ f5) {
    int b = blockIdx.x >> 3, chunk = blockIdx.x & 7;
    int n = chunk * 256 + threadIdx.x;
    if (n >= NN) return;
    float acc = 0.f;
    for (int c = 0; c < CH; ++c) acc += h2[(b * CH + c) * NN + n] * Sv[b * CH + c];
    float Ar = acc * invn[b * NN + n];
    float Dv = (Ar - 1.0f) / (float)NN;
    outD[b * NN + n] = Dv;
    const float* dp = data + (b * NN + n) * 4;
    for (int c = 0; c < 4; ++c) f5[(b * 5 + c) * NN + n] = dp[c];
    f5[(b * 5 + 4) * NN + n] = fmaxf(tanhf(Dv), 0.f);
}

// ---------------------------------------------------------------------------
// kNN stage A: per (b, i, j-chunk) partial top-8 over 250 candidates.
// r12: unroll x2 — two candidates' loads+distances overlap (ILP); inserts
// stay sequential in ascending-j order so selection is bit-identical.
// ---------------------------------------------------------------------------
__global__ __launch_bounds__(256) void k_knn_part(const float* __restrict__ f5,
                                                  float* __restrict__ pd, int* __restrict__ pj) {
    __shared__ float4 fs4[JSZ];
    __shared__ float fs1[JSZ];
    int jc = blockIdx.x, ic = blockIdx.y, b = blockIdx.z;
    int j0 = jc * JSZ;
    int tid = threadIdx.x;
    const float* fb = f5 + b * 5 * NN;
    for (int e = tid; e < JSZ; e += 256) {
        float4 v;
        v.x = fb[0 * NN + j0 + e];
        v.y = fb[1 * NN + j0 + e];
        v.z = fb[2 * NN + j0 + e];
        v.w = fb[3 * NN + j0 + e];
        fs4[e] = v;
        fs1[e] = fb[4 * NN + j0 + e];
    }
    __syncthreads();
    int i = ic * 256 + tid;
    if (i >= NN) return;
    float fi0 = fb[i], fi1 = fb[NN + i], fi2 = fb[2 * NN + i], fi3 = fb[3 * NN + i], fi4 = fb[4 * NN + i];
    float bd[8]; int bj[8];
#pragma unroll
    for (int q = 0; q < 8; ++q) { bd[q] = 1e30f; bj[q] = 0x7fffffff; }
    auto ins = [&](float cd, int cj) {
#pragma unroll
        for (int q = 0; q < 8; ++q) {
            bool lt = cd < bd[q];
            float td = lt ? bd[q] : cd;
            int tj = lt ? bj[q] : cj;
            bd[q] = lt ? cd : bd[q];
            bj[q] = lt ? cj : bj[q];
            cd = td; cj = tj;
        }
    };
    for (int jj = 0; jj < JSZ; jj += 2) {
        float4 fja = fs4[jj];
        float fa4 = fs1[jj];
        float4 fjb = fs4[jj + 1];
        float fb4 = fs1[jj + 1];
        float a0 = fi0 - fja.x, a1 = fi1 - fja.y, a2 = fi2 - fja.z, a3 = fi3 - fja.w, a4 = fi4 - fa4;
        float da = a0 * a0 + a1 * a1 + a2 * a2 + a3 * a3 + a4 * a4;
        float b0 = fi0 - fjb.x, b1 = fi1 - fjb.y, b2 = fi2 - fjb.z, b3 = fi3 - fjb.w, b4 = fi4 - fb4;
        float db = b0 * b0 + b1 * b1 + b2 * b2 + b3 * b3 + b4 * b4;
        int ja = j0 + jj, jb = j0 + jj + 1;
        if (ja != i && da < bd[7]) ins(da, ja);
        if (jb != i && db < bd[7]) ins(db, jb);
    }
    long base = ((long)(b * NN + i) * JCH + jc) * 8;
#pragma unroll
    for (int q = 0; q < 8; ++q) { pd[base + q] = bd[q]; pj[base + q] = bj[q]; }
}

// ---------------------------------------------------------------------------
// r12: fused kNN merge + graph-feature statistics.  Merge thread s produces
// exactly the 8 indices gstats thread s consumes (same grid 125x256, same s
// mapping) — keep them in registers, still write idxb for graphconv.
// Merge tie-break and gstats accumulation order identical to r11.
// ---------------------------------------------------------------------------
__global__ __launch_bounds__(256) void k_knn_gstats(const float* __restrict__ pd, const int* __restrict__ pj,
                                                    const float* __restrict__ f5, int* __restrict__ idxb,
                                                    double* __restrict__ gacc) {
    int s = blockIdx.x * 256 + threadIdx.x;  // b*NN + i
    int bjv[8];
    float acc[65];
#pragma unroll
    for (int q = 0; q < 65; ++q) acc[q] = 0.f;
    if (s < BB * NN) {
        const float* dl = pd + (long)s * JCH * 8;
        const int* jl = pj + (long)s * JCH * 8;
        int ptr[JCH];
#pragma unroll
        for (int c = 0; c < JCH; ++c) ptr[c] = 0;
        for (int q = 0; q < 8; ++q) {
            float best = 1e38f; int bestj = 0x7fffffff; int bc = 0;
#pragma unroll
            for (int c = 0; c < JCH; ++c) {
                if (ptr[c] < 8) {
                    float d = dl[c * 8 + ptr[c]];
                    int j = jl[c * 8 + ptr[c]];
                    if (d < best || (d == best && j < bestj)) { best = d; bestj = j; bc = c; }
                }
            }
            bjv[q] = bestj;
            idxb[s * 8 + q] = bestj;
            ++ptr[bc];
        }
        // ---- gstats (identical math/order to r11's k_gstats) ----
        int b = s / NN, n = s - b * NN;
        float fo[5];
#pragma unroll
        for (int c = 0; c < 5; ++c) fo[c] = f5[(b * 5 + c) * NN + n];
        float sd[5] = {0, 0, 0, 0, 0};
        float sdd[15];
#pragma unroll
        for (int q = 0; q < 15; ++q) sdd[q] = 0.f;
        for (int k = 0; k < 8; ++k) {
            int j = bjv[k];
            float df[5];
#pragma unroll
            for (int c = 0; c < 5; ++c) df[c] = fo[c] - f5[(b * 5 + c) * NN + j];
#pragma unroll
            for (int c = 0; c < 5; ++c) sd[c] += df[c];
            int t = 0;
#pragma unroll
            for (int c = 0; c < 5; ++c)
#pragma unroll
                for (int d2 = c; d2 < 5; ++d2) { sdd[t] += df[c] * df[d2]; ++t; }
        }
#pragma unroll
        for (int c = 0; c < 5; ++c) { acc[c] = 8.f * fo[c]; acc[5 + c] = sd[c]; }
        int t = 10, sc = 0;
        for (int p = 0; p < 10; ++p)
            for (int q = p; q < 10; ++q) {
                float v;
                if (q < 5) v = 8.f * fo[p] * fo[q];
                else if (p < 5) v = fo[p] * sd[q - 5];
                else { v = sdd[sc]; ++sc; }
                acc[t++] = v;
            }
    }
#pragma unroll 1
    for (int q = 0; q < 65; ++q) {
        float v = acc[q];
        for (int off = 32; off > 0; off >>= 1) v += __shfl_down(v, off, 64);
        acc[q] = v;
    }
    __shared__ float sh[4][65];
    int lane = threadIdx.x & 63, wid = threadIdx.x >> 6;
    if (lane == 0) {
        for (int q = 0; q < 65; ++q) sh[wid][q] = acc[q];
    }
    __syncthreads();
    if (threadIdx.x < 65) {
        float tot = sh[0][threadIdx.x] + sh[1][threadIdx.x] + sh[2][threadIdx.x] + sh[3][threadIdx.x];
        atomicAdd(&gacc[threadIdx.x], (double)tot);
    }
}

__global__ void k_gfinal(const double* __restrict__ gacc, const float* __restrict__ w2,
                         const float* __restrict__ b2, float* __restrict__ g2ab) {
    int o = threadIdx.x;
    if (o >= 128) return;
    double inv = 1.0 / (double)(BB * NN * 8);
    double Wr[10];
    for (int c = 0; c < 10; ++c) Wr[c] = (double)w2[o * 10 + c];
    double gm[10];
    for (int c = 0; c < 10; ++c) gm[c] = gacc[c] * inv;
    double b0 = (double)b2[o];
    double mean = b0;
    for (int c = 0; c < 10; ++c) mean += Wr[c] * gm[c];
    double e2 = b0 * b0 + 2.0 * b0 * (mean - b0);
    int t = 10;
    for (int p = 0; p < 10; ++p)
        for (int q = p; q < 10; ++q) {
            double G = gacc[t] * inv; ++t;
            double contrib = Wr[p] * Wr[q] * G;
            e2 += (p == q) ? contrib : 2.0 * contrib;
        }
    double var = e2 - mean * mean;
    double a = 1.0 / sqrt(var + 1e-5);
    g2ab[o] = (float)a;
    g2ab[128 + o] = (float)(-mean * a);
}

// graph conv + max over k + bn + relu (bn commutes with max since scale>0)
__global__ __launch_bounds__(256) void k_graphconv(const float* __restrict__ f5, const int* __restrict__ idxb,
                                                   const float* __restrict__ w2, const float* __restrict__ b2,
                                                   const float* __restrict__ g2ab, float* __restrict__ x0) {
    __shared__ float ws[1280], bs[128];
    __shared__ float fo_s[16][5], fnb_s[16][8][5];
    __shared__ int idxs[16][8];
    int b = blockIdx.x / 125, tile = blockIdx.x % 125;
    int nbase = tile * 16;
    int tid = threadIdx.x;
    for (int e = tid; e < 1280; e += 256) ws[e] = w2[e];
    if (tid < 128) bs[tid] = b2[tid];
    if (tid < 128) { int nn = tid >> 3, k = tid & 7; idxs[nn][k] = idxb[(b * NN + nbase + nn) * 8 + k]; }
    if (tid >= 128 && tid < 208) { int e = tid - 128; int nn = e / 5, c = e % 5; fo_s[nn][c] = f5[(b * 5 + c) * NN + nbase + nn]; }
    __syncthreads();
    for (int e = tid; e < 640; e += 256) {
        int nn = e / 40, r = e % 40, k = r / 5, c = r % 5;
        fnb_s[nn][k][c] = f5[(b * 5 + c) * NN + idxs[nn][k]];
    }
    __syncthreads();
    int nn = tid & 15, og = tid >> 4;
    float fo[5];
#pragma unroll
    for (int c = 0; c < 5; ++c) fo[c] = fo_s[nn][c];
    for (int oo = 0; oo < 8; ++oo) {
        int o = og * 8 + oo;
        float base = bs[o];
        float wn[5];
#pragma unroll
        for (int c = 0; c < 5; ++c) {
            float w1 = ws[o * 10 + c], w5 = ws[o * 10 + 5 + c];
            base += (w1 + w5) * fo[c];
            wn[c] = w5;
        }
        float mx = -1e30f;
        for (int k = 0; k < 8; ++k) {
            float v = base;
#pragma unroll
            for (int c = 0; c < 5; ++c) v -= wn[c] * fnb_s[nn][k][c];
            mx = fmaxf(mx, v);
        }
        float y = fmaxf(g2ab[o] * mx + g2ab[128 + o], 0.f);
        x0[(b * CH + o) * NN + nbase + nn] = y;
    }
}

// ---------------------------------------------------------------------------
// r12: rowstats with last-block finalize.  Grid stays 2048 (full
// parallelism, r8 lesson).  Each block writes its (b,c) stats, fences, and
// bumps a per-channel counter; the 16th arrival runs the EXACT k_finalize
// math for channel c (serial b-loop, identical expressions -> bit-identical
// ab).  Decoupled-lookback-style fencing; no spin (no deadlock possible).
// ---------------------------------------------------------------------------
__global__ void k_rowfin2(const float* __restrict__ src, float* __restrict__ stats,
                          float* __restrict__ ab, int* __restrict__ cnt) {
    int row = blockIdx.x;  // b*128+c
    int c = row & 127;
    const float* p = src + row * NN;
    float s = 0.f, ss = 0.f;
    for (int n = threadIdx.x; n < NN; n += 256) { float v = p[n]; s += v; ss += v * v; }
    s = wred(s); ss = wred(ss);
    __shared__ float sh[8];
    int wid = threadIdx.x >> 6, lane = threadIdx.x & 63;
    if (lane == 0) { sh[wid] = s; sh[4 + wid] = ss; }
    __syncthreads();
    if (threadIdx.x == 0) {
        float S0 = sh[0] + sh[1] + sh[2] + sh[3];
        float SS = sh[4] + sh[5] + sh[6] + sh[7];
        float m = S0 / (float)NN;
        float var = SS / (float)NN - m * m;
        stats[row * 2] = m;
        stats[row * 2 + 1] = var;
        __threadfence();
        int old = atomicAdd(&cnt[c], 1);
        if (old == BB - 1) {
            __threadfence();
            float acc = 0.f;
            for (int b = 0; b < BB; ++b) { float v2 = stats[(b * CH + c) * 2 + 1]; acc += v2 / (v2 + 1e-5f); }
            float vc = acc / (float)BB;
            float sc = rsqrtf(vc + 1e-5f);
            for (int b = 0; b < BB; ++b) {
                float m2 = stats[(b * CH + c) * 2];
                float v2 = stats[(b * CH + c) * 2 + 1];
                float a2 = rsqrtf(v2 + 1e-5f) * sc;
                ab[(b * CH + c) * 2] = a2;
                ab[(b * CH + c) * 2 + 1] = -m2 * a2;
            }
        }
    }
}

__global__ void k_resadd(const float* __restrict__ Bm, const float* __restrict__ ab,
                         const float* __restrict__ x, float* __restrict__ y) {
    int i = blockIdx.x * 256 + threadIdx.x;
    if (i >= BB * CH * NN) return;
    int bc = i / NN;
    float v = ab[bc * 2] * Bm[i] + ab[bc * 2 + 1] + x[i];
    y[i] = fmaxf(v, 0.f);
}

// ---------------------------------------------------------------------------
// logit (separate — r10 lesson: never move work into a smaller grid)
// ---------------------------------------------------------------------------
__global__ void k_logit(const float* __restrict__ x4, const float* __restrict__ wl,
                        const float* __restrict__ bl, float* __restrict__ outLogit) {
    int b = blockIdx.x >> 3, chunk = blockIdx.x & 7;
    int n = chunk * 256 + threadIdx.x;
    if (n >= NN) return;
    float acc = 0.f;
    for (int c = 0; c < CH; ++c) acc += wl[c] * x4[(b * CH + c) * NN + n];
    outLogit[b * NN + n] = acc + bl[0];
}

__global__ __launch_bounds__(256) void k_xwx(const float* __restrict__ logit, const float* __restrict__ x_in,
                                             float* __restrict__ XwX) {
    int b = blockIdx.x;
    int tid = threadIdx.x;
    float a[45];
#pragma unroll
    for (int q = 0; q < 45; ++q) a[q] = 0.f;
    for (int n = tid; n < NN; n += 256) {
        float lg = logit[b * NN + n];
        float w = fmaxf(tanhf(lg), 0.f);
        const float* xp = x_in + (b * NN + n) * 4;
        float px = xp[0], py = xp[1], z = xp[2], wq = xp[3];
        float X9[9] = {z * px, z * py, z, wq * px, wq * py, wq, px, py, 1.f};
        int t = 0;
#pragma unroll
        for (int p = 0; p < 9; ++p) {
            float wp = w * X9[p];
#pragma unroll
            for (int q = p; q < 9; ++q) { a[t] += wp * X9[q]; ++t; }
        }
    }
#pragma unroll 1
    for (int q = 0; q < 45; ++q) {
        float v = a[q];
        for (int off = 32; off > 0; off >>= 1) v += __shfl_down(v, off, 64);
        a[q] = v;
    }
    __shared__ float sh[4][45];
    int lane = tid & 63, wid = tid >> 6;
    if (lane == 0) {
        for (int q = 0; q < 45; ++q) sh[wid][q] = a[q];
    }
    __syncthreads();
    if (tid < 45) XwX[b * 45 + tid] = sh[0][tid] + sh[1][tid] + sh[2][tid] + sh[3][tid];
}

// ---------------------------------------------------------------------------
// 9x9 symmetric eigensolver — faithful LAPACK ssyevd (f32) emulation:
// ssytd2 (lower) + ssteqr + sormtr, f32 LAPACK constants, 3.10+ slartg.
// r10: d/e/tau in lane-indexed registers (readlane + per-lane select),
// rotation-logging + single-column replay.  Verified passing r10/r11.
// ---------------------------------------------------------------------------
__device__ __forceinline__ float lgetf(float reg, int i) {
    return __int_as_float(__builtin_amdgcn_readlane(__float_as_int(reg), i));
}
__device__ __forceinline__ float wsum64(float v) {
    for (int off = 32; off > 0; off >>= 1) v += __shfl_xor(v, off, 64);
    return v;
}

__device__ inline float slapy2_f(float x, float y) {
    float xa = fabsf(x), ya = fabsf(y);
    float w = fmaxf(xa, ya), z = fminf(xa, ya);
    if (z == 0.f) return w;
    float q = z / w;
    return w * sqrtf(1.f + q * q);
}

__device__ inline void slartg_f(float f, float g, float& c, float& s, float& r) {
    if (g == 0.f) { c = 1.f; s = 0.f; r = f; }
    else if (f == 0.f) { c = 0.f; s = (g > 0.f ? 1.f : -1.f); r = fabsf(g); }
    else {
        float d = sqrtf(f * f + g * g);
        c = fabsf(f) / d;
        r = (f >= 0.f) ? d : -d;
        s = g / r;
    }
}

__device__ void slaev2_f(float a, float b, float c, float& rt1, float& rt2, float& cs1, float& sn1) {
    float sm = a + c, df = a - c;
    float adf = fabsf(df), tb = b + b, ab = fabsf(tb);
    float acmx, acmn;
    if (fabsf(a) > fabsf(c)) { acmx = a; acmn = c; } else { acmx = c; acmn = a; }
    float rt;
    if (adf > ab) { float q = ab / adf; rt = adf * sqrtf(1.f + q * q); }
    else if (adf < ab) { float q = adf / ab; rt = ab * sqrtf(1.f + q * q); }
    else rt = ab * sqrtf(2.f);
    int sgn1;
    if (sm < 0.f) { rt1 = 0.5f * (sm - rt); sgn1 = -1; rt2 = (acmx / rt1) * acmn - (b / rt1) * b; }
    else if (sm > 0.f) { rt1 = 0.5f * (sm + rt); sgn1 = 1; rt2 = (acmx / rt1) * acmn - (b / rt1) * b; }
    else { rt1 = 0.5f * rt; rt2 = -0.5f * rt; sgn1 = 1; }
    float cs; int sgn2;
    if (df >= 0.f) { cs = df + rt; sgn2 = 1; } else { cs = df - rt; sgn2 = -1; }
    float acs = fabsf(cs);
    if (acs > ab) {
        float ct = -tb / cs;
        sn1 = 1.f / sqrtf(1.f + ct * ct);
        cs1 = ct * sn1;
    } else {
        if (ab == 0.f) { cs1 = 1.f; sn1 = 0.f; }
        else { float tn = -cs / tb; cs1 = 1.f / sqrtf(1.f + tn * tn); sn1 = tn * cs1; }
    }
    if (sgn1 == sgn2) { float tn = cs1; cs1 = -sn1; sn1 = tn; }
}

#define ROTLOG_MAX 2560

__global__ __launch_bounds__(64) void k_eigh(const float* __restrict__ XwX, float* __restrict__ out_e) {
    __shared__ float Am[81];
    __shared__ float rcl[ROTLOG_MAX], rsl[ROTLOG_MAX];
    __shared__ int rjl[ROTLOG_MAX];
    int bb = blockIdx.x;
    int lane = threadIdx.x;
#define AA(i, j) Am[(i) * 9 + (j)]
#define DGET(i) lgetf(dreg, (i))
#define DSET(i, v) do { float _v = (v); dreg = (lane == (i)) ? _v : dreg; } while (0)
#define EGET(i) lgetf(ereg, (i))
#define ESET(i, v) do { float _v = (v); ereg = (lane == (i)) ? _v : ereg; } while (0)
    {
        const float* src = XwX + bb * 45;
        for (int e2 = lane; e2 < 81; e2 += 64) {
            int r0 = e2 / 9, c0 = e2 % 9;
            int a0 = r0 < c0 ? r0 : c0, b0 = r0 < c0 ? c0 : r0;
            int t = a0 * 9 - (a0 * (a0 - 1)) / 2 + (b0 - a0);
            Am[e2] = src[t];
        }
    }
    __syncthreads();
    float dreg = 0.f, ereg = 0.f, treg = 0.f;
    int cnt = 0;
    for (int i = 0; i < 8; ++i) {
        float alpha = AA(i + 1, i);
        float xn2 = 0.f;
        for (int j = i + 2; j < 9; ++j) xn2 += AA(j, i) * AA(j, i);
        float taui;
        if (xn2 == 0.f) { taui = 0.f; ESET(i, alpha); }
        else {
            float xnorm = sqrtf(xn2);
            float beta = slapy2_f(alpha, xnorm);
            beta = (alpha >= 0.f) ? -beta : beta;
            taui = (beta - alpha) / beta;
            float scl = 1.f / (alpha - beta);
            for (int j = i + 2; j < 9; ++j) AA(j, i) *= scl;
            ESET(i, beta);
            float p[9], w[9];
            for (int j = i + 1; j < 9; ++j) {
                float acc = AA(j, i + 1);
                for (int k2 = i + 2; k2 < 9; ++k2) acc += AA(j, k2) * AA(k2, i);
                p[j] = taui * acc;
            }
            float dot = p[i + 1];
            for (int j = i + 2; j < 9; ++j) dot += p[j] * AA(j, i);
            float alpha2 = -0.5f * taui * dot;
            w[i + 1] = p[i + 1] + alpha2;
            for (int j = i + 2; j < 9; ++j) w[j] = p[j] + alpha2 * AA(j, i);
            for (int j = i + 1; j < 9; ++j) {
                float vj = (j == i + 1) ? 1.f : AA(j, i);
                for (int k2 = i + 1; k2 < 9; ++k2) {
                    float vk = (k2 == i + 1) ? 1.f : AA(k2, i);
                    float upd = AA(j, k2) - (vj * w[k2] + w[j] * vk);
                    __syncthreads();
                    if (lane == 0) AA(j, k2) = upd;
                    __syncthreads();
                }
            }
        }
        treg = (lane == i) ? taui : treg;
    }
    dreg = (lane < 9) ? Am[lane * 10] : 0.f;
    const float eps = 5.9604645e-08f;
    const float eps2 = 3.5527137e-15f;
    const float safmin = 1.17549435e-38f;
    const int n = 9;
    int nmaxit = n * 30, jtot = 0;
    int l1 = 0;
    while (l1 <= n - 1) {
        if (l1 > 0) ESET(l1 - 1, 0.f);
        int m = n - 1;
        for (int mm = l1; mm <= n - 2; ++mm) {
            float tst = fabsf(EGET(mm));
            if (tst == 0.f) { m = mm; break; }
            if (tst <= (sqrtf(fabsf(DGET(mm))) * sqrtf(fabsf(DGET(mm + 1)))) * eps) { ESET(mm, 0.f); m = mm; break; }
        }
        int l = l1, lsv = l, lend = m, lendsv = lend;
        l1 = m + 1;
        if (lend == l) continue;
        if (fabsf(DGET(lend)) < fabsf(DGET(l))) { lend = lsv; l = lendsv; }
        if (lend > l) {
            for (;;) {
                int m2 = lend;
                if (l != lend) {
                    for (int mm = l; mm <= lend - 1; ++mm) {
                        float em = EGET(mm);
                        float tst = em * em;
                        if (tst <= (eps2 * fabsf(DGET(mm))) * fabsf(DGET(mm + 1)) + safmin) { m2 = mm; break; }
                    }
                }
                if (m2 < lend) ESET(m2, 0.f);
                float p = DGET(l);
                if (m2 == l) { DSET(l, p); ++l; if (l <= lend) continue; else break; }
                if (m2 == l + 1) {
                    float rt1, rt2, c, s;
                    slaev2_f(DGET(l), EGET(l), DGET(l + 1), rt1, rt2, c, s);
                    if (lane == 0) { rcl[cnt] = c; rsl[cnt] = s; rjl[cnt] = l; }
                    ++cnt;
                    DSET(l, rt1); DSET(l + 1, rt2); ESET(l, 0.f); l += 2;
                    if (l <= lend) continue; else break;
                }
                if (jtot == nmaxit) break;
                ++jtot;
                float g = (DGET(l + 1) - p) / (2.f * EGET(l));
                float r = slapy2_f(g, 1.f);
                g = DGET(m2) - p + EGET(l) / (g + (g >= 0.f ? fabsf(r) : -fabsf(r)));
                float s = 1.f, c = 1.f;
                p = 0.f;
                for (int i = m2 - 1; i >= l; --i) {
                    float ei = EGET(i);
                    float f = s * ei, bq = c * ei;
                    slartg_f(g, f, c, s, r);
                    if (i != m2 - 1) ESET(i + 1, r);
                    g = DGET(i + 1) - p;
                    r = (DGET(i) - g) * s + 2.f * c * bq;
                    p = s * r;
                    DSET(i + 1, g + p);
                    g = c * r - bq;
                    if (lane == 0) { rcl[cnt] = c; rsl[cnt] = -s; rjl[cnt] = i; }
                    ++cnt;
                }
                DSET(l, DGET(l) - p);
                ESET(l, g);
            }
        } else {
            for (;;) {
                int m2 = lend;
                if (l != lend) {
                    for (int mm = l; mm >= lend + 1; --mm) {
                        float em = EGET(mm - 1);
                        float tst = em * em;
                        if (tst <= (eps2 * fabsf(DGET(mm))) * fabsf(DGET(mm - 1)) + safmin) { m2 = mm; break; }
                    }
                }
                if (m2 > lend) ESET(m2 - 1, 0.f);
                float p = DGET(l);
                if (m2 == l) { DSET(l, p); --l; if (l >= lend) continue; else break; }
                if (m2 == l - 1) {
                    float rt1, rt2, c, s;
                    slaev2_f(DGET(l - 1), EGET(l - 1), DGET(l), rt1, rt2, c, s);
                    if (lane == 0) { rcl[cnt] = c; rsl[cnt] = s; rjl[cnt] = l - 1; }
                    ++cnt;
                    DSET(l - 1, rt1); DSET(l, rt2); ESET(l - 1, 0.f); l -= 2;
                    if (l >= lend) continue; else break;
                }
                if (jtot == nmaxit) break;
                ++jtot;
                float g = (DGET(l - 1) - p) / (2.f * EGET(l - 1));
                float r = slapy2_f(g, 1.f);
                g = DGET(m2) - p + EGET(l - 1) / (g + (g >= 0.f ? fabsf(r) : -fabsf(r)));
                float s = 1.f, c = 1.f;
                p = 0.f;
                for (int i = m2; i <= l - 1; ++i) {
                    float ei = EGET(i);
                    float f = s * ei, bq = c * ei;
                    slartg_f(g, f, c, s, r);
                    if (i != m2) ESET(i - 1, r);
                    g = DGET(i) - p;
                    r = (DGET(i + 1) - g) * s + 2.f * c * bq;
                    p = s * r;
                    DSET(i, g + p);
                    g = c * r - bq;
                    if (lane == 0) { rcl[cnt] = c; rsl[cnt] = s; rjl[cnt] = i; }
                    ++cnt;
                }
                DSET(l, DGET(l) - p);
                ESET(l - 1, g);
            }
        }
    }
    __syncthreads();
    int permreg = lane;
    for (int ii = 1; ii < 9; ++ii) {
        int i = ii - 1, kk = i;
        float p = DGET(i);
        for (int j = ii; j < 9; ++j) {
            float dj = DGET(j);
            if (dj < p) { kk = j; p = dj; }
        }
        if (kk != i) {
            float di = DGET(i);
            DSET(kk, di);
            DSET(i, p);
            int pi = __builtin_amdgcn_readlane(permreg, i);
            int pk = __builtin_amdgcn_readlane(permreg, kk);
            permreg = (lane == i) ? pk : permreg;
            permreg = (lane == kk) ? pi : permreg;
        }
    }
    int kcol = __builtin_amdgcn_readlane(permreg, 0);
    float v0reg = (lane == kcol) ? 1.f : 0.f;
    for (int t = cnt - 1; t >= 0; --t) {
        float c = rcl[t], s = rsl[t];
        int j = rjl[t];
        float a = lgetf(v0reg, j);
        float b2 = lgetf(v0reg, j + 1);
        float nj = c * a - s * b2;
        float nj1 = s * a + c * b2;
        v0reg = (lane == j) ? nj : v0reg;
        v0reg = (lane == j + 1) ? nj1 : v0reg;
    }
    for (int i = 7; i >= 0; --i) {
        float ti = lgetf(treg, i);
        if (ti == 0.f) continue;
        float avi = (lane >= i + 2 && lane <= 8) ? Am[lane * 9 + i] : 0.f;
        float contrib = 0.f;
        if (lane == i + 1) contrib = v0reg;
        else if (lane >= i + 2 && lane <= 8) contrib = avi * v0reg;
        float dot = wsum64(contrib) * ti;
        if (lane == i + 1) v0reg -= dot;
        else if (lane >= i + 2 && lane <= 8) v0reg -= avi * dot;
    }
    float sq = (lane < 9) ? v0reg * v0reg : 0.f;
    float nrm = sqrtf(wsum64(sq));
    if (lane < 9) out_e[bb * 9 + lane] = v0reg / nrm;
#undef AA
#undef DGET
#undef DSET
#undef EGET
#undef ESET
}

// ---------------------------------------------------------------------------
// launch
// ---------------------------------------------------------------------------
extern "C" void kernel_launch(void* const* d_in, const int* in_sizes, int n_in,
                              void* d_out, int out_size, void* d_ws, size_t ws_size,
                              hipStream_t stream) {
    const float* data = (const float*)d_in[0];
    const float* x_in = (const float*)d_in[1];
    const float* w1a = (const float*)d_in[2];
    const float* b1a = (const float*)d_in[3];
    const float* w1b = (const float*)d_in[4];
    const float* b1b = (const float*)d_in[5];
    const float* w2 = (const float*)d_in[6];
    const float* b2 = (const float*)d_in[7];
    const float* res_wa = (const float*)d_in[8];
    const float* res_ba = (const float*)d_in[9];
    const float* res_wb = (const float*)d_in[10];
    const float* res_bb = (const float*)d_in[11];
    const float* wl = (const float*)d_in[12];
    const float* bl = (const float*)d_in[13];
    float* out = (float*)d_out;

    // workspace layout
    double* gacc = (double*)d_ws;                       // 65 doubles (zeroed)
    float* xwx = (float*)((char*)d_ws + 1024);          // 16*45 floats
    int* counters = (int*)((char*)d_ws + 4096);         // 8 x 128 ints (zeroed)
    float* fbase = (float*)((char*)d_ws + 16384);
    float* big0 = fbase;
    float* big1 = big0 + BB * CH * NN;
    float* big2 = big1 + BB * CH * NN;
    float* tbuf = big2 + BB * CH * NN;  // unused
    float* f5 = tbuf + BB * 4 * NN;
    float* invn = f5 + BB * 5 * NN;
    float* Sv = invn + BB * NN;
    int* idxb = (int*)(Sv + BB * CH);
    float* chAB = (float*)(idxb + BB * NN * 8);
    float* stA = chAB + 256;
    float* abA = stA + BB * CH * 2;
    float* stB = abA + BB * CH * 2;
    float* abB = stB + BB * CH * 2;
    float* g2ab = abB + BB * CH * 2;
    // kNN partials live in big2 (free until the res-blocks)
    float* knn_pd = big2;
    int* knn_pj = (int*)(big2 + BB * NN * JCH * 8);

    hipMemsetAsync(d_ws, 0, 16384, stream);

    k_conv1<<<16000, 256, 0, stream>>>(data, w1a, b1a, big0);
    k_chanstats<<<128, 256, 0, stream>>>(big0, chAB);
    k_gemm<<<dim3(2, 512), 256, 0, stream>>>(big0, w1b, b1b, big1, chAB, 1);  // h2 in big1
    k_invn<<<128, 256, 0, stream>>>(big1, invn);
    k_S<<<2048, 256, 0, stream>>>(big1, invn, Sv);
    k_Df<<<128, 256, 0, stream>>>(big1, invn, Sv, data, out, f5);
    k_knn_part<<<dim3(JCH, 8, BB), 256, 0, stream>>>(f5, knn_pd, knn_pj);
    k_knn_gstats<<<125, 256, 0, stream>>>(knn_pd, knn_pj, f5, idxb, gacc);
    k_gfinal<<<1, 128, 0, stream>>>(gacc, w2, b2, g2ab);
    k_graphconv<<<2000, 256, 0, stream>>>(f5, idxb, w2, b2, g2ab, big0);  // x0 in big0

    float* xb = big0;
    float* hb = big1;
    for (int i = 0; i < 4; ++i) {
        k_gemm<<<dim3(2, 512), 256, 0, stream>>>(xb, res_wa + i * CH * CH, res_ba + i * CH, hb, nullptr, 0);
        k_rowfin2<<<2048, 256, 0, stream>>>(hb, stA, abA, counters + (i * 2) * 128);
        k_gemm<<<dim3(2, 512), 256, 0, stream>>>(hb, res_wb + i * CH * CH, res_bb + i * CH, big2, abA, 2);
        k_rowfin2<<<2048, 256, 0, stream>>>(big2, stB, abB, counters + (i * 2 + 1) * 128);
        k_resadd<<<16000, 256, 0, stream>>>(big2, abB, xb, hb);
        float* tmp = xb; xb = hb; hb = tmp;
    }

    k_logit<<<128, 256, 0, stream>>>(xb, wl, bl, out + BB * NN);
    k_xwx<<<16, 256, 0, stream>>>(out + BB * NN, x_in, xwx);
    k_eigh<<<16, 64, 0, stream>>>(xwx, out + 2 * BB * NN);
}

// Round 13
// 815.393 us; speedup vs baseline: 1.3016x; 1.3016x over previous
//
#include <hip/hip_runtime.h>
#include <math.h>

#define BB 16
#define NN 2000
#define CH 128
#define KNN 8
#define JCH 8
#define JSZ 250  // NN / JCH

// ---------------------------------------------------------------------------
// helpers
// ---------------------------------------------------------------------------
__device__ inline float wred(float v) {
    for (int off = 32; off > 0; off >>= 1) v += __shfl_down(v, off, 64);
    return v;
}

// conv1: c1[b,o,n] = sum_c w1a[o,c]*data[b,n,c] + b1a[o]
__global__ void k_conv1(const float* __restrict__ data, const float* __restrict__ w1a,
                        const float* __restrict__ b1a, float* __restrict__ c1) {
    int i = blockIdx.x * 256 + threadIdx.x;  // (b*128+o)*N+n
    if (i >= BB * CH * NN) return;
    int n = i % NN;
    int rest = i / NN;
    int o = rest & 127;
    int b = rest >> 7;
    const float* dp = data + (b * NN + n) * 4;
    float acc = b1a[o];
    for (int c = 0; c < 4; ++c) acc += w1a[o * 4 + c] * dp[c];
    c1[i] = acc;
}

// per-channel bn stats over (b,n): 128 blocks
__global__ void k_chanstats(const float* __restrict__ src, float* __restrict__ chAB) {
    int o = blockIdx.x;
    int tid = threadIdx.x;
    float s = 0.f, ss = 0.f;
    for (int b = 0; b < BB; ++b) {
        const float* p = src + (b * CH + o) * NN;
        for (int n = tid; n < NN; n += 256) { float v = p[n]; s += v; ss += v * v; }
    }
    s = wred(s); ss = wred(ss);
    __shared__ float sh[8];
    int wid = tid >> 6, lane = tid & 63;
    if (lane == 0) { sh[wid] = s; sh[4 + wid] = ss; }
    __syncthreads();
    if (tid == 0) {
        float S0 = sh[0] + sh[1] + sh[2] + sh[3];
        float SS = sh[4] + sh[5] + sh[6] + sh[7];
        float m = S0 / (float)(BB * NN);
        float var = SS / (float)(BB * NN) - m * m;
        float a = rsqrtf(var + 1e-5f);
        chAB[o] = a;
        chAB[CH + o] = -m * a;
    }
}

// ---------------------------------------------------------------------------
// generic 128x128 GEMM over columns (b,n), with input transform.
// FMA accumulation order IDENTICAL to the r3 baseline — do not reorder.
// ---------------------------------------------------------------------------
__global__ __launch_bounds__(256) void k_gemm(const float* __restrict__ X, const float* __restrict__ W,
                                              const float* __restrict__ bias, float* __restrict__ Y,
                                              const float* __restrict__ ab, int mode) {
    int ot = blockIdx.x, by = blockIdx.y;
    int b = by >> 5, nt = by & 31;
    int n0 = nt * 64, o0 = ot * 64;
    int tid = threadIdx.x;
    int tx = tid & 15, ty = tid >> 4;
    __shared__ float Xs[32][64];
    __shared__ float Ws[32][68];
    float acc[4][4] = {};
    for (int jc = 0; jc < 4; ++jc) {
        for (int q = 0; q < 8; ++q) {
            int e = q * 256 + tid;
            int jj = e >> 6, nn = e & 63;
            int j = jc * 32 + jj, n = n0 + nn;
            float v = 0.f;
            if (n < NN) {
                v = X[(b * CH + j) * NN + n];
                if (mode == 1) v = fmaxf(ab[j] * v + ab[CH + j], 0.f);
                else if (mode == 2) { int bc = b * CH + j; v = fmaxf(ab[bc * 2] * v + ab[bc * 2 + 1], 0.f); }
            }
            Xs[jj][nn] = v;
        }
        for (int q = 0; q < 8; ++q) {
            int e = q * 256 + tid;
            int jj = e & 31, oo = e >> 5;
            Ws[jj][oo] = W[(o0 + oo) * CH + jc * 32 + jj];
        }
        __syncthreads();
        for (int jj = 0; jj < 32; ++jj) {
            float4 wv = *(const float4*)&Ws[jj][ty * 4];
            float4 xv = *(const float4*)&Xs[jj][tx * 4];
            float wva[4] = {wv.x, wv.y, wv.z, wv.w};
            float xva[4] = {xv.x, xv.y, xv.z, xv.w};
#pragma unroll
            for (int a = 0; a < 4; ++a)
#pragma unroll
                for (int bq = 0; bq < 4; ++bq) acc[a][bq] += wva[a] * xva[bq];
        }
        __syncthreads();
    }
    for (int a = 0; a < 4; ++a) {
        int o = o0 + ty * 4 + a;
        float bi = bias[o];
        for (int q = 0; q < 4; ++q) {
            int n = n0 + tx * 4 + q;
            if (n < NN) Y[(b * CH + o) * NN + n] = acc[a][q] + bi;
        }
    }
}

// ---------------------------------------------------------------------------
// stage 1 tail: channel-norm, S, D, f5
// ---------------------------------------------------------------------------
__global__ void k_invn(const float* __restrict__ h2, float* __restrict__ invn) {
    int b = blockIdx.x >> 3, chunk = blockIdx.x & 7;
    int n = chunk * 256 + threadIdx.x;
    if (n >= NN) return;
    float acc = 0.f;
    for (int c = 0; c < CH; ++c) { float v = h2[(b * CH + c) * NN + n]; acc += v * v; }
    invn[b * NN + n] = 1.f / (sqrtf(acc) + 1e-5f);
}

__global__ void k_S(const float* __restrict__ h2, const float* __restrict__ invn, float* __restrict__ Sv) {
    int row = blockIdx.x;  // b*128+c
    int b = row >> 7;
    const float* p = h2 + row * NN;
    const float* iv = invn + b * NN;
    float s = 0.f;
    for (int n = threadIdx.x; n < NN; n += 256) s += p[n] * iv[n];
    s = wred(s);
    __shared__ float sh[4];
    int wid = threadIdx.x >> 6, lane = threadIdx.x & 63;
    if (lane == 0) sh[wid] = s;
    __syncthreads();
    if (threadIdx.x == 0) Sv[row] = sh[0] + sh[1] + sh[2] + sh[3];
}

__global__ void k_Df(const float* __restrict__ h2, const float* __restrict__ invn,
                     const float* __restrict__ Sv, const float* __restrict__ data,
                     float* __restrict__ outD, float* __restrict__ f5) {
    int b = blockIdx.x >> 3, chunk = blockIdx.x & 7;
    int n = chunk * 256 + threadIdx.x;
    if (n >= NN) return;
    float acc = 0.f;
    for (int c = 0; c < CH; ++c) acc += h2[(b * CH + c) * NN + n] * Sv[b * CH + c];
    float Ar = acc * invn[b * NN + n];
    float Dv = (Ar - 1.0f) / (float)NN;
    outD[b * NN + n] = Dv;
    const float* dp = data + (b * NN + n) * 4;
    for (int c = 0; c < 4; ++c) f5[(b * 5 + c) * NN + n] = dp[c];
    f5[(b * 5 + 4) * NN + n] = fmaxf(tanhf(Dv), 0.f);
}

// ---------------------------------------------------------------------------
// kNN stage A: per (b, i, j-chunk) partial top-8 over 250 candidates.
// unroll x2 (r12, verified: 116 -> 98.6 us); selection bit-identical.
// ---------------------------------------------------------------------------
__global__ __launch_bounds__(256) void k_knn_part(const float* __restrict__ f5,
                                                  float* __restrict__ pd, int* __restrict__ pj) {
    __shared__ float4 fs4[JSZ];
    __shared__ float fs1[JSZ];
    int jc = blockIdx.x, ic = blockIdx.y, b = blockIdx.z;
    int j0 = jc * JSZ;
    int tid = threadIdx.x;
    const float* fb = f5 + b * 5 * NN;
    for (int e = tid; e < JSZ; e += 256) {
        float4 v;
        v.x = fb[0 * NN + j0 + e];
        v.y = fb[1 * NN + j0 + e];
        v.z = fb[2 * NN + j0 + e];
        v.w = fb[3 * NN + j0 + e];
        fs4[e] = v;
        fs1[e] = fb[4 * NN + j0 + e];
    }
    __syncthreads();
    int i = ic * 256 + tid;
    if (i >= NN) return;
    float fi0 = fb[i], fi1 = fb[NN + i], fi2 = fb[2 * NN + i], fi3 = fb[3 * NN + i], fi4 = fb[4 * NN + i];
    float bd[8]; int bj[8];
#pragma unroll
    for (int q = 0; q < 8; ++q) { bd[q] = 1e30f; bj[q] = 0x7fffffff; }
    auto ins = [&](float cd, int cj) {
#pragma unroll
        for (int q = 0; q < 8; ++q) {
            bool lt = cd < bd[q];
            float td = lt ? bd[q] : cd;
            int tj = lt ? bj[q] : cj;
            bd[q] = lt ? cd : bd[q];
            bj[q] = lt ? cj : bj[q];
            cd = td; cj = tj;
        }
    };
    for (int jj = 0; jj < JSZ; jj += 2) {
        float4 fja = fs4[jj];
        float fa4 = fs1[jj];
        float4 fjb = fs4[jj + 1];
        float fb4 = fs1[jj + 1];
        float a0 = fi0 - fja.x, a1 = fi1 - fja.y, a2 = fi2 - fja.z, a3 = fi3 - fja.w, a4 = fi4 - fa4;
        float da = a0 * a0 + a1 * a1 + a2 * a2 + a3 * a3 + a4 * a4;
        float b0 = fi0 - fjb.x, b1 = fi1 - fjb.y, b2 = fi2 - fjb.z, b3 = fi3 - fjb.w, b4 = fi4 - fb4;
        float db = b0 * b0 + b1 * b1 + b2 * b2 + b3 * b3 + b4 * b4;
        int ja = j0 + jj, jb = j0 + jj + 1;
        if (ja != i && da < bd[7]) ins(da, ja);
        if (jb != i && db < bd[7]) ins(db, jb);
    }
    long base = ((long)(b * NN + i) * JCH + jc) * 8;
#pragma unroll
    for (int q = 0; q < 8; ++q) { pd[base + q] = bd[q]; pj[base + q] = bj[q]; }
}

// kNN stage B: 8-way merge of sorted partial lists (separate kernel — r12's
// fusion with gstats spilled registers and regressed; reverted).
__global__ __launch_bounds__(256) void k_knn_merge(const float* __restrict__ pd, const int* __restrict__ pj,
                                                   int* __restrict__ idxb) {
    int s = blockIdx.x * 256 + threadIdx.x;  // b*NN + i
    if (s >= BB * NN) return;
    const float* dl = pd + (long)s * JCH * 8;
    const int* jl = pj + (long)s * JCH * 8;
    int ptr[JCH];
#pragma unroll
    for (int c = 0; c < JCH; ++c) ptr[c] = 0;
    for (int q = 0; q < 8; ++q) {
        float best = 1e38f; int bestj = 0x7fffffff; int bc = 0;
#pragma unroll
        for (int c = 0; c < JCH; ++c) {
            if (ptr[c] < 8) {
                float d = dl[c * 8 + ptr[c]];
                int j = jl[c * 8 + ptr[c]];
                if (d < best || (d == best && j < bestj)) { best = d; bestj = j; bc = c; }
            }
        }
        idxb[s * 8 + q] = bestj;
        ++ptr[bc];
    }
}

// ---------------------------------------------------------------------------
// graph-feature statistics: 10 means + 55 second moments (f64 accumulators)
// ---------------------------------------------------------------------------
__global__ __launch_bounds__(256) void k_gstats(const float* __restrict__ f5, const int* __restrict__ idxb,
                                                double* __restrict__ gacc) {
    int s = blockIdx.x * 256 + threadIdx.x;
    float acc[65];
#pragma unroll
    for (int q = 0; q < 65; ++q) acc[q] = 0.f;
    if (s < BB * NN) {
        int b = s / NN, n = s - b * NN;
        float fo[5];
#pragma unroll
        for (int c = 0; c < 5; ++c) fo[c] = f5[(b * 5 + c) * NN + n];
        float sd[5] = {0, 0, 0, 0, 0};
        float sdd[15];
#pragma unroll
        for (int q = 0; q < 15; ++q) sdd[q] = 0.f;
        for (int k = 0; k < 8; ++k) {
            int j = idxb[s * 8 + k];
            float df[5];
#pragma unroll
            for (int c = 0; c < 5; ++c) df[c] = fo[c] - f5[(b * 5 + c) * NN + j];
#pragma unroll
            for (int c = 0; c < 5; ++c) sd[c] += df[c];
            int t = 0;
#pragma unroll
            for (int c = 0; c < 5; ++c)
#pragma unroll
                for (int d2 = c; d2 < 5; ++d2) { sdd[t] += df[c] * df[d2]; ++t; }
        }
#pragma unroll
        for (int c = 0; c < 5; ++c) { acc[c] = 8.f * fo[c]; acc[5 + c] = sd[c]; }
        int t = 10, sc = 0;
        for (int p = 0; p < 10; ++p)
            for (int q = p; q < 10; ++q) {
                float v;
                if (q < 5) v = 8.f * fo[p] * fo[q];
                else if (p < 5) v = fo[p] * sd[q - 5];
                else { v = sdd[sc]; ++sc; }
                acc[t++] = v;
            }
    }
#pragma unroll 1
    for (int q = 0; q < 65; ++q) {
        float v = acc[q];
        for (int off = 32; off > 0; off >>= 1) v += __shfl_down(v, off, 64);
        acc[q] = v;
    }
    __shared__ float sh[4][65];
    int lane = threadIdx.x & 63, wid = threadIdx.x >> 6;
    if (lane == 0) {
        for (int q = 0; q < 65; ++q) sh[wid][q] = acc[q];
    }
    __syncthreads();
    if (threadIdx.x < 65) {
        float tot = sh[0][threadIdx.x] + sh[1][threadIdx.x] + sh[2][threadIdx.x] + sh[3][threadIdx.x];
        atomicAdd(&gacc[threadIdx.x], (double)tot);
    }
}

__global__ void k_gfinal(const double* __restrict__ gacc, const float* __restrict__ w2,
                         const float* __restrict__ b2, float* __restrict__ g2ab) {
    int o = threadIdx.x;
    if (o >= 128) return;
    double inv = 1.0 / (double)(BB * NN * 8);
    double Wr[10];
    for (int c = 0; c < 10; ++c) Wr[c] = (double)w2[o * 10 + c];
    double gm[10];
    for (int c = 0; c < 10; ++c) gm[c] = gacc[c] * inv;
    double b0 = (double)b2[o];
    double mean = b0;
    for (int c = 0; c < 10; ++c) mean += Wr[c] * gm[c];
    double e2 = b0 * b0 + 2.0 * b0 * (mean - b0);
    int t = 10;
    for (int p = 0; p < 10; ++p)
        for (int q = p; q < 10; ++q) {
            double G = gacc[t] * inv; ++t;
            double contrib = Wr[p] * Wr[q] * G;
            e2 += (p == q) ? contrib : 2.0 * contrib;
        }
    double var = e2 - mean * mean;
    double a = 1.0 / sqrt(var + 1e-5);
    g2ab[o] = (float)a;
    g2ab[128 + o] = (float)(-mean * a);
}

// graph conv + max over k + bn + relu (bn commutes with max since scale>0)
__global__ __launch_bounds__(256) void k_graphconv(const float* __restrict__ f5, const int* __restrict__ idxb,
                                                   const float* __restrict__ w2, const float* __restrict__ b2,
                                                   const float* __restrict__ g2ab, float* __restrict__ x0) {
    __shared__ float ws[1280], bs[128];
    __shared__ float fo_s[16][5], fnb_s[16][8][5];
    __shared__ int idxs[16][8];
    int b = blockIdx.x / 125, tile = blockIdx.x % 125;
    int nbase = tile * 16;
    int tid = threadIdx.x;
    for (int e = tid; e < 1280; e += 256) ws[e] = w2[e];
    if (tid < 128) bs[tid] = b2[tid];
    if (tid < 128) { int nn = tid >> 3, k = tid & 7; idxs[nn][k] = idxb[(b * NN + nbase + nn) * 8 + k]; }
    if (tid >= 128 && tid < 208) { int e = tid - 128; int nn = e / 5, c = e % 5; fo_s[nn][c] = f5[(b * 5 + c) * NN + nbase + nn]; }
    __syncthreads();
    for (int e = tid; e < 640; e += 256) {
        int nn = e / 40, r = e % 40, k = r / 5, c = r % 5;
        fnb_s[nn][k][c] = f5[(b * 5 + c) * NN + idxs[nn][k]];
    }
    __syncthreads();
    int nn = tid & 15, og = tid >> 4;
    float fo[5];
#pragma unroll
    for (int c = 0; c < 5; ++c) fo[c] = fo_s[nn][c];
    for (int oo = 0; oo < 8; ++oo) {
        int o = og * 8 + oo;
        float base = bs[o];
        float wn[5];
#pragma unroll
        for (int c = 0; c < 5; ++c) {
            float w1 = ws[o * 10 + c], w5 = ws[o * 10 + 5 + c];
            base += (w1 + w5) * fo[c];
            wn[c] = w5;
        }
        float mx = -1e30f;
        for (int k = 0; k < 8; ++k) {
            float v = base;
#pragma unroll
            for (int c = 0; c < 5; ++c) v -= wn[c] * fnb_s[nn][k][c];
            mx = fmaxf(mx, v);
        }
        float y = fmaxf(g2ab[o] * mx + g2ab[128 + o], 0.f);
        x0[(b * CH + o) * NN + nbase + nn] = y;
    }
}

// ---------------------------------------------------------------------------
// res-block support — r11 structure (r12's last-block finalize added a
// serial latency tail at each dispatch end and regressed; reverted).
// ---------------------------------------------------------------------------
__global__ void k_rowstats(const float* __restrict__ src, float* __restrict__ stats) {
    int row = blockIdx.x;  // b*128+c
    const float* p = src + row * NN;
    float s = 0.f, ss = 0.f;
    for (int n = threadIdx.x; n < NN; n += 256) { float v = p[n]; s += v; ss += v * v; }
    s = wred(s); ss = wred(ss);
    __shared__ float sh[8];
    int wid = threadIdx.x >> 6, lane = threadIdx.x & 63;
    if (lane == 0) { sh[wid] = s; sh[4 + wid] = ss; }
    __syncthreads();
    if (threadIdx.x == 0) {
        float S0 = sh[0] + sh[1] + sh[2] + sh[3];
        float SS = sh[4] + sh[5] + sh[6] + sh[7];
        float m = S0 / (float)NN;
        float var = SS / (float)NN - m * m;
        stats[row * 2] = m;
        stats[row * 2 + 1] = var;
    }
}

__global__ void k_finalize(const float* __restrict__ stats, float* __restrict__ ab) {
    int c = threadIdx.x;
    if (c >= 128) return;
    float acc = 0.f;
    for (int b = 0; b < BB; ++b) { float var = stats[(b * CH + c) * 2 + 1]; acc += var / (var + 1e-5f); }
    float vc = acc / (float)BB;
    float sc = rsqrtf(vc + 1e-5f);
    for (int b = 0; b < BB; ++b) {
        float m = stats[(b * CH + c) * 2];
        float var = stats[(b * CH + c) * 2 + 1];
        float a = rsqrtf(var + 1e-5f) * sc;
        ab[(b * CH + c) * 2] = a;
        ab[(b * CH + c) * 2 + 1] = -m * a;
    }
}

__global__ void k_resadd(const float* __restrict__ Bm, const float* __restrict__ ab,
                         const float* __restrict__ x, float* __restrict__ y) {
    int i = blockIdx.x * 256 + threadIdx.x;
    if (i >= BB * CH * NN) return;
    int bc = i / NN;
    float v = ab[bc * 2] * Bm[i] + ab[bc * 2 + 1] + x[i];
    y[i] = fmaxf(v, 0.f);
}

// ---------------------------------------------------------------------------
// logit (separate — r10 lesson: never move work into a smaller grid)
// ---------------------------------------------------------------------------
__global__ void k_logit(const float* __restrict__ x4, const float* __restrict__ wl,
                        const float* __restrict__ bl, float* __restrict__ outLogit) {
    int b = blockIdx.x >> 3, chunk = blockIdx.x & 7;
    int n = chunk * 256 + threadIdx.x;
    if (n >= NN) return;
    float acc = 0.f;
    for (int c = 0; c < CH; ++c) acc += wl[c] * x4[(b * CH + c) * NN + n];
    outLogit[b * NN + n] = acc + bl[0];
}

__global__ __launch_bounds__(256) void k_xwx(const float* __restrict__ logit, const float* __restrict__ x_in,
                                             float* __restrict__ XwX) {
    int b = blockIdx.x;
    int tid = threadIdx.x;
    float a[45];
#pragma unroll
    for (int q = 0; q < 45; ++q) a[q] = 0.f;
    for (int n = tid; n < NN; n += 256) {
        float lg = logit[b * NN + n];
        float w = fmaxf(tanhf(lg), 0.f);
        const float* xp = x_in + (b * NN + n) * 4;
        float px = xp[0], py = xp[1], z = xp[2], wq = xp[3];
        float X9[9] = {z * px, z * py, z, wq * px, wq * py, wq, px, py, 1.f};
        int t = 0;
#pragma unroll
        for (int p = 0; p < 9; ++p) {
            float wp = w * X9[p];
#pragma unroll
            for (int q = p; q < 9; ++q) { a[t] += wp * X9[q]; ++t; }
        }
    }
#pragma unroll 1
    for (int q = 0; q < 45; ++q) {
        float v = a[q];
        for (int off = 32; off > 0; off >>= 1) v += __shfl_down(v, off, 64);
        a[q] = v;
    }
    __shared__ float sh[4][45];
    int lane = tid & 63, wid = tid >> 6;
    if (lane == 0) {
        for (int q = 0; q < 45; ++q) sh[wid][q] = a[q];
    }
    __syncthreads();
    if (tid < 45) XwX[b * 45 + tid] = sh[0][tid] + sh[1][tid] + sh[2][tid] + sh[3][tid];
}

// ---------------------------------------------------------------------------
// 9x9 symmetric eigensolver — faithful LAPACK ssyevd (f32) emulation:
// ssytd2 (lower) + ssteqr + sormtr, f32 LAPACK constants, 3.10+ slartg.
// d/e/tau in lane-indexed registers; rotation-logging + single-column
// replay.  Verified passing r10/r11 — do not touch.
// ---------------------------------------------------------------------------
__device__ __forceinline__ float lgetf(float reg, int i) {
    return __int_as_float(__builtin_amdgcn_readlane(__float_as_int(reg), i));
}
__device__ __forceinline__ float wsum64(float v) {
    for (int off = 32; off > 0; off >>= 1) v += __shfl_xor(v, off, 64);
    return v;
}

__device__ inline float slapy2_f(float x, float y) {
    float xa = fabsf(x), ya = fabsf(y);
    float w = fmaxf(xa, ya), z = fminf(xa, ya);
    if (z == 0.f) return w;
    float q = z / w;
    return w * sqrtf(1.f + q * q);
}

__device__ inline void slartg_f(float f, float g, float& c, float& s, float& r) {
    if (g == 0.f) { c = 1.f; s = 0.f; r = f; }
    else if (f == 0.f) { c = 0.f; s = (g > 0.f ? 1.f : -1.f); r = fabsf(g); }
    else {
        float d = sqrtf(f * f + g * g);
        c = fabsf(f) / d;
        r = (f >= 0.f) ? d : -d;
        s = g / r;
    }
}

__device__ void slaev2_f(float a, float b, float c, float& rt1, float& rt2, float& cs1, float& sn1) {
    float sm = a + c, df = a - c;
    float adf = fabsf(df), tb = b + b, ab = fabsf(tb);
    float acmx, acmn;
    if (fabsf(a) > fabsf(c)) { acmx = a; acmn = c; } else { acmx = c; acmn = a; }
    float rt;
    if (adf > ab) { float q = ab / adf; rt = adf * sqrtf(1.f + q * q); }
    else if (adf < ab) { float q = adf / ab; rt = ab * sqrtf(1.f + q * q); }
    else rt = ab * sqrtf(2.f);
    int sgn1;
    if (sm < 0.f) { rt1 = 0.5f * (sm - rt); sgn1 = -1; rt2 = (acmx / rt1) * acmn - (b / rt1) * b; }
    else if (sm > 0.f) { rt1 = 0.5f * (sm + rt); sgn1 = 1; rt2 = (acmx / rt1) * acmn - (b / rt1) * b; }
    else { rt1 = 0.5f * rt; rt2 = -0.5f * rt; sgn1 = 1; }
    float cs; int sgn2;
    if (df >= 0.f) { cs = df + rt; sgn2 = 1; } else { cs = df - rt; sgn2 = -1; }
    float acs = fabsf(cs);
    if (acs > ab) {
        float ct = -tb / cs;
        sn1 = 1.f / sqrtf(1.f + ct * ct);
        cs1 = ct * sn1;
    } else {
        if (ab == 0.f) { cs1 = 1.f; sn1 = 0.f; }
        else { float tn = -cs / tb; cs1 = 1.f / sqrtf(1.f + tn * tn); sn1 = tn * cs1; }
    }
    if (sgn1 == sgn2) { float tn = cs1; cs1 = -sn1; sn1 = tn; }
}

#define ROTLOG_MAX 2560

__global__ __launch_bounds__(64) void k_eigh(const float* __restrict__ XwX, float* __restrict__ out_e) {
    __shared__ float Am[81];
    __shared__ float rcl[ROTLOG_MAX], rsl[ROTLOG_MAX];
    __shared__ int rjl[ROTLOG_MAX];
    int bb = blockIdx.x;
    int lane = threadIdx.x;
#define AA(i, j) Am[(i) * 9 + (j)]
#define DGET(i) lgetf(dreg, (i))
#define DSET(i, v) do { float _v = (v); dreg = (lane == (i)) ? _v : dreg; } while (0)
#define EGET(i) lgetf(ereg, (i))
#define ESET(i, v) do { float _v = (v); ereg = (lane == (i)) ? _v : ereg; } while (0)
    {
        const float* src = XwX + bb * 45;
        for (int e2 = lane; e2 < 81; e2 += 64) {
            int r0 = e2 / 9, c0 = e2 % 9;
            int a0 = r0 < c0 ? r0 : c0, b0 = r0 < c0 ? c0 : r0;
            int t = a0 * 9 - (a0 * (a0 - 1)) / 2 + (b0 - a0);
            Am[e2] = src[t];
        }
    }
    __syncthreads();
    float dreg = 0.f, ereg = 0.f, treg = 0.f;
    int cnt = 0;
    for (int i = 0; i < 8; ++i) {
        float alpha = AA(i + 1, i);
        float xn2 = 0.f;
        for (int j = i + 2; j < 9; ++j) xn2 += AA(j, i) * AA(j, i);
        float taui;
        if (xn2 == 0.f) { taui = 0.f; ESET(i, alpha); }
        else {
            float xnorm = sqrtf(xn2);
            float beta = slapy2_f(alpha, xnorm);
            beta = (alpha >= 0.f) ? -beta : beta;
            taui = (beta - alpha) / beta;
            float scl = 1.f / (alpha - beta);
            for (int j = i + 2; j < 9; ++j) AA(j, i) *= scl;
            ESET(i, beta);
            float p[9], w[9];
            for (int j = i + 1; j < 9; ++j) {
                float acc = AA(j, i + 1);
                for (int k2 = i + 2; k2 < 9; ++k2) acc += AA(j, k2) * AA(k2, i);
                p[j] = taui * acc;
            }
            float dot = p[i + 1];
            for (int j = i + 2; j < 9; ++j) dot += p[j] * AA(j, i);
            float alpha2 = -0.5f * taui * dot;
            w[i + 1] = p[i + 1] + alpha2;
            for (int j = i + 2; j < 9; ++j) w[j] = p[j] + alpha2 * AA(j, i);
            for (int j = i + 1; j < 9; ++j) {
                float vj = (j == i + 1) ? 1.f : AA(j, i);
                for (int k2 = i + 1; k2 < 9; ++k2) {
                    float vk = (k2 == i + 1) ? 1.f : AA(k2, i);
                    float upd = AA(j, k2) - (vj * w[k2] + w[j] * vk);
                    __syncthreads();
                    if (lane == 0) AA(j, k2) = upd;
                    __syncthreads();
                }
            }
        }
        treg = (lane == i) ? taui : treg;
    }
    dreg = (lane < 9) ? Am[lane * 10] : 0.f;
    const float eps = 5.9604645e-08f;
    const float eps2 = 3.5527137e-15f;
    const float safmin = 1.17549435e-38f;
    const int n = 9;
    int nmaxit = n * 30, jtot = 0;
    int l1 = 0;
    while (l1 <= n - 1) {
        if (l1 > 0) ESET(l1 - 1, 0.f);
        int m = n - 1;
        for (int mm = l1; mm <= n - 2; ++mm) {
            float tst = fabsf(EGET(mm));
            if (tst == 0.f) { m = mm; break; }
            if (tst <= (sqrtf(fabsf(DGET(mm))) * sqrtf(fabsf(DGET(mm + 1)))) * eps) { ESET(mm, 0.f); m = mm; break; }
        }
        int l = l1, lsv = l, lend = m, lendsv = lend;
        l1 = m + 1;
        if (lend == l) continue;
        if (fabsf(DGET(lend)) < fabsf(DGET(l))) { lend = lsv; l = lendsv; }
        if (lend > l) {
            for (;;) {
                int m2 = lend;
                if (l != lend) {
                    for (int mm = l; mm <= lend - 1; ++mm) {
                        float em = EGET(mm);
                        float tst = em * em;
                        if (tst <= (eps2 * fabsf(DGET(mm))) * fabsf(DGET(mm + 1)) + safmin) { m2 = mm; break; }
                    }
                }
                if (m2 < lend) ESET(m2, 0.f);
                float p = DGET(l);
                if (m2 == l) { DSET(l, p); ++l; if (l <= lend) continue; else break; }
                if (m2 == l + 1) {
                    float rt1, rt2, c, s;
                    slaev2_f(DGET(l), EGET(l), DGET(l + 1), rt1, rt2, c, s);
                    if (lane == 0) { rcl[cnt] = c; rsl[cnt] = s; rjl[cnt] = l; }
                    ++cnt;
                    DSET(l, rt1); DSET(l + 1, rt2); ESET(l, 0.f); l += 2;
                    if (l <= lend) continue; else break;
                }
                if (jtot == nmaxit) break;
                ++jtot;
                float g = (DGET(l + 1) - p) / (2.f * EGET(l));
                float r = slapy2_f(g, 1.f);
                g = DGET(m2) - p + EGET(l) / (g + (g >= 0.f ? fabsf(r) : -fabsf(r)));
                float s = 1.f, c = 1.f;
                p = 0.f;
                for (int i = m2 - 1; i >= l; --i) {
                    float ei = EGET(i);
                    float f = s * ei, bq = c * ei;
                    slartg_f(g, f, c, s, r);
                    if (i != m2 - 1) ESET(i + 1, r);
                    g = DGET(i + 1) - p;
                    r = (DGET(i) - g) * s + 2.f * c * bq;
                    p = s * r;
                    DSET(i + 1, g + p);
                    g = c * r - bq;
                    if (lane == 0) { rcl[cnt] = c; rsl[cnt] = -s; rjl[cnt] = i; }
                    ++cnt;
                }
                DSET(l, DGET(l) - p);
                ESET(l, g);
            }
        } else {
            for (;;) {
                int m2 = lend;
                if (l != lend) {
                    for (int mm = l; mm >= lend + 1; --mm) {
                        float em = EGET(mm - 1);
                        float tst = em * em;
                        if (tst <= (eps2 * fabsf(DGET(mm))) * fabsf(DGET(mm - 1)) + safmin) { m2 = mm; break; }
                    }
                }
                if (m2 > lend) ESET(m2 - 1, 0.f);
                float p = DGET(l);
                if (m2 == l) { DSET(l, p); --l; if (l >= lend) continue; else break; }
                if (m2 == l - 1) {
                    float rt1, rt2, c, s;
                    slaev2_f(DGET(l - 1), EGET(l - 1), DGET(l), rt1, rt2, c, s);
                    if (lane == 0) { rcl[cnt] = c; rsl[cnt] = s; rjl[cnt] = l - 1; }
                    ++cnt;
                    DSET(l - 1, rt1); DSET(l, rt2); ESET(l - 1, 0.f); l -= 2;
                    if (l >= lend) continue; else break;
                }
                if (jtot == nmaxit) break;
                ++jtot;
                float g = (DGET(l - 1) - p) / (2.f * EGET(l - 1));
                float r = slapy2_f(g, 1.f);
                g = DGET(m2) - p + EGET(l - 1) / (g + (g >= 0.f ? fabsf(r) : -fabsf(r)));
                float s = 1.f, c = 1.f;
                p = 0.f;
                for (int i = m2; i <= l - 1; ++i) {
                    float ei = EGET(i);
                    float f = s * ei, bq = c * ei;
                    slartg_f(g, f, c, s, r);
                    if (i != m2) ESET(i - 1, r);
                    g = DGET(i) - p;
                    r = (DGET(i + 1) - g) * s + 2.f * c * bq;
                    p = s * r;
                    DSET(i, g + p);
                    g = c * r - bq;
                    if (lane == 0) { rcl[cnt] = c; rsl[cnt] = s; rjl[cnt] = i; }
                    ++cnt;
                }
                DSET(l, DGET(l) - p);
                ESET(l - 1, g);
            }
        }
    }
    __syncthreads();
    int permreg = lane;
    for (int ii = 1; ii < 9; ++ii) {
        int i = ii - 1, kk = i;
        float p = DGET(i);
        for (int j = ii; j < 9; ++j) {
            float dj = DGET(j);
            if (dj < p) { kk = j; p = dj; }
        }
        if (kk != i) {
            float di = DGET(i);
            DSET(kk, di);
            DSET(i, p);
            int pi = __builtin_amdgcn_readlane(permreg, i);
            int pk = __builtin_amdgcn_readlane(permreg, kk);
            permreg = (lane == i) ? pk : permreg;
            permreg = (lane == kk) ? pi : permreg;
        }
    }
    int kcol = __builtin_amdgcn_readlane(permreg, 0);
    float v0reg = (lane == kcol) ? 1.f : 0.f;
    for (int t = cnt - 1; t >= 0; --t) {
        float c = rcl[t], s = rsl[t];
        int j = rjl[t];
        float a = lgetf(v0reg, j);
        float b2 = lgetf(v0reg, j + 1);
        float nj = c * a - s * b2;
        float nj1 = s * a + c * b2;
        v0reg = (lane == j) ? nj : v0reg;
        v0reg = (lane == j + 1) ? nj1 : v0reg;
    }
    for (int i = 7; i >= 0; --i) {
        float ti = lgetf(treg, i);
        if (ti == 0.f) continue;
        float avi = (lane >= i + 2 && lane <= 8) ? Am[lane * 9 + i] : 0.f;
        float contrib = 0.f;
        if (lane == i + 1) contrib = v0reg;
        else if (lane >= i + 2 && lane <= 8) contrib = avi * v0reg;
        float dot = wsum64(contrib) * ti;
        if (lane == i + 1) v0reg -= dot;
        else if (lane >= i + 2 && lane <= 8) v0reg -= avi * dot;
    }
    float sq = (lane < 9) ? v0reg * v0reg : 0.f;
    float nrm = sqrtf(wsum64(sq));
    if (lane < 9) out_e[bb * 9 + lane] = v0reg / nrm;
#undef AA
#undef DGET
#undef DSET
#undef EGET
#undef ESET
}

// ---------------------------------------------------------------------------
// launch
// ---------------------------------------------------------------------------
extern "C" void kernel_launch(void* const* d_in, const int* in_sizes, int n_in,
                              void* d_out, int out_size, void* d_ws, size_t ws_size,
                              hipStream_t stream) {
    const float* data = (const float*)d_in[0];
    const float* x_in = (const float*)d_in[1];
    const float* w1a = (const float*)d_in[2];
    const float* b1a = (const float*)d_in[3];
    const float* w1b = (const float*)d_in[4];
    const float* b1b = (const float*)d_in[5];
    const float* w2 = (const float*)d_in[6];
    const float* b2 = (const float*)d_in[7];
    const float* res_wa = (const float*)d_in[8];
    const float* res_ba = (const float*)d_in[9];
    const float* res_wb = (const float*)d_in[10];
    const float* res_bb = (const float*)d_in[11];
    const float* wl = (const float*)d_in[12];
    const float* bl = (const float*)d_in[13];
    float* out = (float*)d_out;

    // workspace layout
    double* gacc = (double*)d_ws;                       // 65 doubles (zeroed)
    float* xwx = (float*)((char*)d_ws + 1024);          // 16*45 floats
    float* fbase = (float*)((char*)d_ws + 16384);
    float* big0 = fbase;
    float* big1 = big0 + BB * CH * NN;
    float* big2 = big1 + BB * CH * NN;
    float* tbuf = big2 + BB * CH * NN;  // unused
    float* f5 = tbuf + BB * 4 * NN;
    float* invn = f5 + BB * 5 * NN;
    float* Sv = invn + BB * NN;
    int* idxb = (int*)(Sv + BB * CH);
    float* chAB = (float*)(idxb + BB * NN * 8);
    float* stA = chAB + 256;
    float* abA = stA + BB * CH * 2;
    float* stB = abA + BB * CH * 2;
    float* abB = stB + BB * CH * 2;
    float* g2ab = abB + BB * CH * 2;
    // kNN partials live in big2 (free until the res-blocks)
    float* knn_pd = big2;
    int* knn_pj = (int*)(big2 + BB * NN * JCH * 8);

    hipMemsetAsync(d_ws, 0, 1024, stream);

    k_conv1<<<16000, 256, 0, stream>>>(data, w1a, b1a, big0);
    k_chanstats<<<128, 256, 0, stream>>>(big0, chAB);
    k_gemm<<<dim3(2, 512), 256, 0, stream>>>(big0, w1b, b1b, big1, chAB, 1);  // h2 in big1
    k_invn<<<128, 256, 0, stream>>>(big1, invn);
    k_S<<<2048, 256, 0, stream>>>(big1, invn, Sv);
    k_Df<<<128, 256, 0, stream>>>(big1, invn, Sv, data, out, f5);
    k_knn_part<<<dim3(JCH, 8, BB), 256, 0, stream>>>(f5, knn_pd, knn_pj);
    k_knn_merge<<<125, 256, 0, stream>>>(knn_pd, knn_pj, idxb);
    k_gstats<<<125, 256, 0, stream>>>(f5, idxb, gacc);
    k_gfinal<<<1, 128, 0, stream>>>(gacc, w2, b2, g2ab);
    k_graphconv<<<2000, 256, 0, stream>>>(f5, idxb, w2, b2, g2ab, big0);  // x0 in big0

    float* xb = big0;
    float* hb = big1;
    for (int i = 0; i < 4; ++i) {
        k_gemm<<<dim3(2, 512), 256, 0, stream>>>(xb, res_wa + i * CH * CH, res_ba + i * CH, hb, nullptr, 0);
        k_rowstats<<<2048, 256, 0, stream>>>(hb, stA);
        k_finalize<<<1, 128, 0, stream>>>(stA, abA);
        k_gemm<<<dim3(2, 512), 256, 0, stream>>>(hb, res_wb + i * CH * CH, res_bb + i * CH, big2, abA, 2);
        k_rowstats<<<2048, 256, 0, stream>>>(big2, stB);
        k_finalize<<<1, 128, 0, stream>>>(stB, abB);
        k_resadd<<<16000, 256, 0, stream>>>(big2, abB, xb, hb);
        float* tmp = xb; xb = hb; hb = tmp;
    }

    k_logit<<<128, 256, 0, stream>>>(xb, wl, bl, out + BB * NN);
    k_xwx<<<16, 256, 0, stream>>>(out + BB * NN, x_in, xwx);
    k_eigh<<<16, 64, 0, stream>>>(xwx, out + 2 * BB * NN);
}